// Round 2
// baseline (1109.651 us; speedup 1.0000x reference)
//
#include <hip/hip_runtime.h>
#include <stdint.h>

#define AS1 __attribute__((address_space(1)))
#define AS3 __attribute__((address_space(3)))

typedef float f32x4 __attribute__((ext_vector_type(4)));
typedef short s16x8 __attribute__((ext_vector_type(8)));
typedef unsigned short ushort_t;

static constexpr int D    = 1024;   // embedding dim
static constexpr int H    = 2048;   // expert hidden
static constexpr int E    = 8;      // experts
static constexpr int NTOK = 8192;   // B*S
static constexpr int HS   = 4096;   // shared hidden
static constexpr int MAXROWS = NTOK * 2 + E * 128;  // 17408 worst-case padded routed rows
static constexpr int MAXBLK  = MAXROWS / 128;       // 136

__device__ __forceinline__ ushort_t f2bf(float f) {
  union { float f; unsigned u; } v; v.f = f;
  unsigned r = v.u + 0x7fffu + ((v.u >> 16) & 1u);   // RNE
  return (ushort_t)(r >> 16);
}
__device__ __forceinline__ float bf2f(ushort_t h) {
  union { unsigned u; float f; } v; v.u = ((unsigned)h) << 16;
  return v.f;
}

// ---------------- f32 -> bf16 conversion ----------------
__global__ void f2bf_kernel(const float* __restrict__ src, ushort_t* __restrict__ dst, int n4) {
  int i = blockIdx.x * blockDim.x + threadIdx.x;
  int stride = gridDim.x * blockDim.x;
  for (; i < n4; i += stride) {
    float4 v = ((const float4*)src)[i];
    ushort4 o;
    o.x = f2bf(v.x); o.y = f2bf(v.y); o.z = f2bf(v.z); o.w = f2bf(v.w);
    ((ushort4*)dst)[i] = o;
  }
}

// ---------------- routing ----------------
// meta ints: [0..7] counts, [8..15] padded offsets, [16] total padded rows,
//            [17] nblk, [18..18+MAXBLK) blk->expert
__global__ void zero_counts(int* meta) { if (threadIdx.x < E) meta[threadIdx.x] = 0; }

__global__ void gate_kernel(const float* __restrict__ x, const float* __restrict__ gw,
                            const float* __restrict__ gb, int* __restrict__ te,
                            int* __restrict__ trank, float* __restrict__ tw,
                            int* __restrict__ meta) {
  int t = blockIdx.x, lane = threadIdx.x;  // 64 threads
  const float* xr = x + (size_t)t * D;
  float acc[E];
#pragma unroll
  for (int e = 0; e < E; ++e) acc[e] = 0.f;
  for (int it = 0; it < D / 64; ++it) {
    int d = lane + it * 64;
    float xd = xr[d];
#pragma unroll
    for (int e = 0; e < E; ++e) acc[e] += xd * gw[e * D + d];
  }
#pragma unroll
  for (int e = 0; e < E; ++e)
    for (int s = 32; s > 0; s >>= 1) acc[e] += __shfl_down(acc[e], s);
  if (lane == 0) {
    float lg[E], m = -1e30f;
#pragma unroll
    for (int e = 0; e < E; ++e) { lg[e] = acc[e] + gb[e]; m = fmaxf(m, lg[e]); }
    float z = 0.f, p[E];
#pragma unroll
    for (int e = 0; e < E; ++e) { p[e] = expf(lg[e] - m); z += p[e]; }
#pragma unroll
    for (int e = 0; e < E; ++e) p[e] /= z;
    int i0 = 0;
#pragma unroll
    for (int e = 1; e < E; ++e) if (p[e] > p[i0]) i0 = e;
    int i1 = (i0 == 0) ? 1 : 0;
#pragma unroll
    for (int e = 0; e < E; ++e) if (e != i0 && p[e] > p[i1]) i1 = e;
    float s = p[i0] + p[i1] + 1e-20f;
    int r0 = atomicAdd(&meta[i0], 1);
    int r1 = atomicAdd(&meta[i1], 1);
    te[2 * t] = i0; te[2 * t + 1] = i1;
    trank[2 * t] = r0; trank[2 * t + 1] = r1;
    tw[2 * t] = p[i0] / s; tw[2 * t + 1] = p[i1] / s;
  }
}

__global__ void offsets_kernel(int* meta) {
  if (threadIdx.x != 0 || blockIdx.x != 0) return;
  int off = 0;
  for (int e = 0; e < E; ++e) {
    meta[8 + e] = off;
    int nb = (meta[e] + 127) >> 7;
    int b0 = off >> 7;
    for (int b = 0; b < nb; ++b) meta[18 + b0 + b] = e;
    off += nb << 7;
  }
  meta[16] = off;
  meta[17] = off >> 7;
}

__global__ void scatter_kernel(const int* __restrict__ te, const int* __restrict__ trank,
                               const float* __restrict__ tw, const int* __restrict__ meta,
                               int* __restrict__ tok_list, float* __restrict__ slot_w) {
  int i = blockIdx.x * blockDim.x + threadIdx.x;
  if (i >= NTOK * 2) return;
  int e = te[i];
  int slot = meta[8 + e] + trank[i];
  tok_list[slot] = i >> 1;
  slot_w[slot] = tw[i];
}

// ---------------- bf16 MFMA GEMM: C[M,N] = A @ W^T (+ bias) ----------------
// A: [*, K] bf16 (rows optionally gathered via tok_list)
// W: [E?, N, K] bf16 row-major (torch Linear layout)
// 128x128 tile, BK=64, 4 waves, each 64x64 via 4x4 of 16x16x32 MFMA.
// Epilogue modes:
enum { EP_BF16 = 0, EP_SILU = 1, EP_F32 = 2, EP_SCATTER = 3 };

template <bool ROUTED, bool GATHER, int EP>
__global__ __launch_bounds__(256, 2)
void gemm_bt(const ushort_t* __restrict__ A, const ushort_t* __restrict__ Wb,
             const float* __restrict__ bias, void* __restrict__ Cv,
             int N, int K,
             const int* __restrict__ meta, const int* __restrict__ tok_list,
             const float* __restrict__ slot_w, float* __restrict__ out) {
  int bm = blockIdx.y, bn = blockIdx.x;
  const ushort_t* Wp = Wb;
  const float* bp = bias;
  int rowend = 0x7fffffff;
  if (ROUTED) {
    if (bm >= meta[17]) return;
    int e = meta[18 + bm];
    Wp += (size_t)e * N * K;
    bp += (size_t)e * N;
    rowend = meta[8 + e] + meta[e];
  }
  __shared__ __align__(16) ushort_t As[128 * 64];
  __shared__ __align__(16) ushort_t Bs[128 * 64];
  int tid = threadIdx.x, wave = tid >> 6, lane = tid & 63;

  // staging: per wave 4 A-chunks + 4 B-chunks of 64 lanes x 16B (8 rows x 64 cols each)
  const ushort_t* agp[4];
  const ushort_t* bgp[4];
  ushort_t* alp[4];
  ushort_t* blp[4];
#pragma unroll
  for (int j = 0; j < 4; ++j) {
    int sr = (wave * 4 + j) * 8 + (lane >> 3);   // 0..127 row within tile
    int c = (lane & 7) * 8;                      // 0..56 col (bf16 elems)
    int slot = bm * 128 + sr;
    int arow;
    if (GATHER) arow = (slot < rowend) ? tok_list[slot] : 0;
    else        arow = slot;
    agp[j] = A + (size_t)arow * K + c;
    bgp[j] = Wp + (size_t)(bn * 128 + sr) * K + c;
    alp[j] = &As[(wave * 4 + j) * 512];
    blp[j] = &Bs[(wave * 4 + j) * 512];
  }

  f32x4 acc[4][4];
  const f32x4 zero = {0.f, 0.f, 0.f, 0.f};
#pragma unroll
  for (int i = 0; i < 4; ++i)
#pragma unroll
    for (int j = 0; j < 4; ++j) acc[i][j] = zero;

  int wm = wave >> 1, wn = wave & 1;
  int fr = lane & 15, fq = lane >> 4;
  int aoff[4], boff[4];
#pragma unroll
  for (int i = 0; i < 4; ++i) aoff[i] = (wm * 64 + i * 16 + fr) * 64 + fq * 8;
#pragma unroll
  for (int j = 0; j < 4; ++j) boff[j] = (wn * 64 + j * 16 + fr) * 64 + fq * 8;

  for (int k0 = 0; k0 < K; k0 += 64) {
#pragma unroll
    for (int j = 0; j < 4; ++j) {
      __builtin_amdgcn_global_load_lds((const AS1 unsigned*)(agp[j] + k0), (AS3 unsigned*)alp[j], 16, 0, 0);
      __builtin_amdgcn_global_load_lds((const AS1 unsigned*)(bgp[j] + k0), (AS3 unsigned*)blp[j], 16, 0, 0);
    }
    __syncthreads();
#pragma unroll
    for (int kk = 0; kk < 64; kk += 32) {
      s16x8 af[4], bfr[4];
#pragma unroll
      for (int i = 0; i < 4; ++i) af[i] = *(const s16x8*)&As[aoff[i] + kk];
#pragma unroll
      for (int j = 0; j < 4; ++j) bfr[j] = *(const s16x8*)&Bs[boff[j] + kk];
#pragma unroll
      for (int i = 0; i < 4; ++i)
#pragma unroll
        for (int j = 0; j < 4; ++j)
          acc[i][j] = __builtin_amdgcn_mfma_f32_16x16x32_bf16(af[i], bfr[j], acc[i][j], 0, 0, 0);
    }
    __syncthreads();
  }

  // epilogue: C/D layout col=lane&15, row=(lane>>4)*4+reg
  float bv[4];
  int ccol[4];
#pragma unroll
  for (int j = 0; j < 4; ++j) {
    ccol[j] = bn * 128 + wn * 64 + j * 16 + fr;
    bv[j] = bp[ccol[j]];
  }
#pragma unroll
  for (int i = 0; i < 4; ++i) {
    int row0 = bm * 128 + wm * 64 + i * 16 + fq * 4;
#pragma unroll
    for (int r = 0; r < 4; ++r) {
      int row = row0 + r;
      if (EP == EP_SCATTER) {
        if (row < rowend) {
          int token = tok_list[row];
          float w = slot_w[row];
          size_t ob = (size_t)token * N;
#pragma unroll
          for (int j = 0; j < 4; ++j)
            atomicAdd(&out[ob + ccol[j]], w * (acc[i][j][r] + bv[j]));
        }
      } else {
        size_t rb = (size_t)row * N;
#pragma unroll
        for (int j = 0; j < 4; ++j) {
          float v = acc[i][j][r] + bv[j];
          if (EP == EP_F32) {
            ((float*)Cv)[rb + ccol[j]] = v;
          } else if (EP == EP_SILU) {
            float g1 = bf2f(((const ushort_t*)Cv)[rb + ccol[j]]);
            float hv = g1 / (1.f + expf(-g1)) * v;
            ((ushort_t*)Cv)[rb + ccol[j]] = f2bf(hv);
          } else {
            ((ushort_t*)Cv)[rb + ccol[j]] = f2bf(v);
          }
        }
      }
    }
  }
}

extern "C" void kernel_launch(void* const* d_in, const int* in_sizes, int n_in,
                              void* d_out, int out_size, void* d_ws, size_t ws_size,
                              hipStream_t stream) {
  const float* x   = (const float*)d_in[0];
  const float* gw  = (const float*)d_in[1];
  const float* gb  = (const float*)d_in[2];
  const float* w1  = (const float*)d_in[3];
  const float* b1  = (const float*)d_in[4];
  const float* w2  = (const float*)d_in[5];
  const float* b2  = (const float*)d_in[6];
  const float* w3  = (const float*)d_in[7];
  const float* b3  = (const float*)d_in[8];
  const float* sw1 = (const float*)d_in[9];
  const float* sb1 = (const float*)d_in[10];
  const float* sw2 = (const float*)d_in[11];
  const float* sb2 = (const float*)d_in[12];
  const float* sw3 = (const float*)d_in[13];
  const float* sb3 = (const float*)d_in[14];
  float* out = (float*)d_out;
  (void)in_sizes; (void)n_in; (void)out_size; (void)ws_size;

  char* ws = (char*)d_ws;
  size_t o = 0;
  auto alloc = [&](size_t bytes) -> void* {
    void* p = ws + o;
    o = (o + bytes + 255) & ~(size_t)255;
    return p;
  };
  // total ~122 MB
  ushort_t* Xb   = (ushort_t*)alloc((size_t)NTOK * D * 2);          // 16 MB
  ushort_t* Wbuf = (ushort_t*)alloc((size_t)E * H * D * 2);         // 32 MB, reused 6x
  ushort_t* Hb   = (ushort_t*)alloc((size_t)MAXROWS * H * 2);       // 68 MB (also shared [8192,4096])
  int*   meta     = (int*)alloc(1024);
  int*   tok_list = (int*)alloc((size_t)MAXROWS * 4);
  float* slot_w   = (float*)alloc((size_t)MAXROWS * 4);
  int*   te       = (int*)alloc((size_t)NTOK * 2 * 4);
  int*   trank    = (int*)alloc((size_t)NTOK * 2 * 4);
  float* tw       = (float*)alloc((size_t)NTOK * 2 * 4);

  auto conv = [&](const float* s, ushort_t* dp, size_t n) {
    int n4 = (int)(n / 4);
    int blocks = (n4 + 255) / 256;
    if (blocks > 2048) blocks = 2048;
    f2bf_kernel<<<blocks, 256, 0, stream>>>(s, dp, n4);
  };

  // routing (uses f32 x directly)
  zero_counts<<<1, 64, 0, stream>>>(meta);
  gate_kernel<<<NTOK, 64, 0, stream>>>(x, gw, gb, te, trank, tw, meta);
  offsets_kernel<<<1, 1, 0, stream>>>(meta);
  scatter_kernel<<<(NTOK * 2 + 255) / 256, 256, 0, stream>>>(te, trank, tw, meta, tok_list, slot_w);

  conv(x, Xb, (size_t)NTOK * D);

  // ---- shared expert first: writes d_out (f32, overwrite) ----
  conv(sw1, Wbuf, (size_t)HS * D);
  gemm_bt<false, false, EP_BF16><<<dim3(HS / 128, NTOK / 128), 256, 0, stream>>>(
      Xb, Wbuf, sb1, (void*)Hb, HS, D, nullptr, nullptr, nullptr, nullptr);
  conv(sw3, Wbuf, (size_t)HS * D);
  gemm_bt<false, false, EP_SILU><<<dim3(HS / 128, NTOK / 128), 256, 0, stream>>>(
      Xb, Wbuf, sb3, (void*)Hb, HS, D, nullptr, nullptr, nullptr, nullptr);
  conv(sw2, Wbuf, (size_t)D * HS);
  gemm_bt<false, false, EP_F32><<<dim3(D / 128, NTOK / 128), 256, 0, stream>>>(
      Hb, Wbuf, sb2, (void*)d_out, D, HS, nullptr, nullptr, nullptr, nullptr);

  // ---- routed experts: atomic-add into d_out ----
  conv(w1, Wbuf, (size_t)E * H * D);
  gemm_bt<true, true, EP_BF16><<<dim3(H / 128, MAXBLK), 256, 0, stream>>>(
      Xb, Wbuf, b1, (void*)Hb, H, D, meta, tok_list, nullptr, nullptr);
  conv(w3, Wbuf, (size_t)E * H * D);
  gemm_bt<true, true, EP_SILU><<<dim3(H / 128, MAXBLK), 256, 0, stream>>>(
      Xb, Wbuf, b3, (void*)Hb, H, D, meta, tok_list, nullptr, nullptr);
  conv(w2, Wbuf, (size_t)E * D * H);
  gemm_bt<true, false, EP_SCATTER><<<dim3(D / 128, MAXBLK), 256, 0, stream>>>(
      Hb, Wbuf, b2, nullptr, D, H, meta, tok_list, slot_w, out);
}

// Round 3
// 937.973 us; speedup vs baseline: 1.1830x; 1.1830x over previous
//
#include <hip/hip_runtime.h>
#include <stdint.h>

#define AS1 __attribute__((address_space(1)))
#define AS3 __attribute__((address_space(3)))

typedef float f32x4 __attribute__((ext_vector_type(4)));
typedef short s16x8 __attribute__((ext_vector_type(8)));
typedef unsigned short ushort_t;

static constexpr int D    = 1024;   // embedding dim
static constexpr int H    = 2048;   // expert hidden
static constexpr int E    = 8;      // experts
static constexpr int NTOK = 8192;   // B*S
static constexpr int HS   = 4096;   // shared hidden
static constexpr int MAXROWS = NTOK * 2 + E * 128;  // 17408 worst-case padded routed rows
static constexpr int MAXBLK  = MAXROWS / 128;       // 136

__device__ __forceinline__ ushort_t f2bf(float f) {
  union { float f; unsigned u; } v; v.f = f;
  unsigned r = v.u + 0x7fffu + ((v.u >> 16) & 1u);   // RNE
  return (ushort_t)(r >> 16);
}
__device__ __forceinline__ float bf2f(ushort_t h) {
  union { unsigned u; float f; } v; v.u = ((unsigned)h) << 16;
  return v.f;
}

// ---------------- f32 -> bf16 conversion ----------------
__global__ void f2bf_kernel(const float* __restrict__ src, ushort_t* __restrict__ dst, int n4) {
  int i = blockIdx.x * blockDim.x + threadIdx.x;
  int stride = gridDim.x * blockDim.x;
  for (; i < n4; i += stride) {
    float4 v = ((const float4*)src)[i];
    ushort4 o;
    o.x = f2bf(v.x); o.y = f2bf(v.y); o.z = f2bf(v.z); o.w = f2bf(v.w);
    ((ushort4*)dst)[i] = o;
  }
}

// ---------------- routing ----------------
// meta ints: [0..7] counts, [8..15] padded offsets, [16] total padded rows,
//            [17] nblk, [18..18+MAXBLK) blk->expert
__global__ void zero_counts(int* meta) { if (threadIdx.x < E) meta[threadIdx.x] = 0; }

// gate: NO atomics — per-token top2 + weights only. 4 waves/block, wave = token.
__global__ void gate2_kernel(const float* __restrict__ x, const float* __restrict__ gw,
                             const float* __restrict__ gb, int* __restrict__ te,
                             float* __restrict__ tw) {
  int wave = threadIdx.x >> 6, lane = threadIdx.x & 63;
  int t = blockIdx.x * 4 + wave;
  const float* xr = x + (size_t)t * D;
  float acc[E];
#pragma unroll
  for (int e = 0; e < E; ++e) acc[e] = 0.f;
  for (int it = 0; it < D / 64; ++it) {
    int d = lane + it * 64;
    float xd = xr[d];
#pragma unroll
    for (int e = 0; e < E; ++e) acc[e] += xd * gw[e * D + d];
  }
#pragma unroll
  for (int e = 0; e < E; ++e)
    for (int s = 32; s > 0; s >>= 1) acc[e] += __shfl_down(acc[e], s);
  if (lane == 0) {
    float lg[E], m = -1e30f;
#pragma unroll
    for (int e = 0; e < E; ++e) { lg[e] = acc[e] + gb[e]; m = fmaxf(m, lg[e]); }
    float z = 0.f, p[E];
#pragma unroll
    for (int e = 0; e < E; ++e) { p[e] = expf(lg[e] - m); z += p[e]; }
#pragma unroll
    for (int e = 0; e < E; ++e) p[e] /= z;
    int i0 = 0;
#pragma unroll
    for (int e = 1; e < E; ++e) if (p[e] > p[i0]) i0 = e;
    int i1 = (i0 == 0) ? 1 : 0;
#pragma unroll
    for (int e = 0; e < E; ++e) if (e != i0 && p[e] > p[i1]) i1 = e;
    float s = p[i0] + p[i1] + 1e-20f;
    te[2 * t] = i0; te[2 * t + 1] = i1;
    tw[2 * t] = p[i0] / s; tw[2 * t + 1] = p[i1] / s;
  }
}

// rank: two-level aggregation. 32 blocks x 256 threads, 2 entries/thread.
// LDS histogram via LDS atomics -> one global atomic per expert per block.
__global__ void rank_kernel(const int* __restrict__ te, int* __restrict__ trank,
                            int* __restrict__ meta) {
  __shared__ int hist[E];
  __shared__ int base[E];
  int tid = threadIdx.x;
  if (tid < E) hist[tid] = 0;
  __syncthreads();
  int i0 = blockIdx.x * 512 + tid;
  int i1 = i0 + 256;
  int e0 = te[i0], e1 = te[i1];
  int l0 = atomicAdd(&hist[e0], 1);
  int l1 = atomicAdd(&hist[e1], 1);
  __syncthreads();
  if (tid < E) base[tid] = atomicAdd(&meta[tid], hist[tid]);
  __syncthreads();
  trank[i0] = base[e0] + l0;
  trank[i1] = base[e1] + l1;
}

__global__ void offsets_kernel(int* meta) {
  if (threadIdx.x != 0 || blockIdx.x != 0) return;
  int off = 0;
  for (int e = 0; e < E; ++e) {
    meta[8 + e] = off;
    int nb = (meta[e] + 127) >> 7;
    int b0 = off >> 7;
    for (int b = 0; b < nb; ++b) meta[18 + b0 + b] = e;
    off += nb << 7;
  }
  meta[16] = off;
  meta[17] = off >> 7;
}

__global__ void scatter_kernel(const int* __restrict__ te, const int* __restrict__ trank,
                               const float* __restrict__ tw, const int* __restrict__ meta,
                               int* __restrict__ tok_list, float* __restrict__ slot_w) {
  int i = blockIdx.x * blockDim.x + threadIdx.x;
  if (i >= NTOK * 2) return;
  int e = te[i];
  int slot = meta[8 + e] + trank[i];
  tok_list[slot] = i >> 1;
  slot_w[slot] = tw[i];
}

// ---------------- bf16 MFMA GEMM: C[M,N] = A @ W^T (+ bias) ----------------
// A: [*, K] bf16 (rows optionally gathered via tok_list)
// W: [E?, N, K] bf16 row-major (torch Linear layout)
// 128x128 tile, BK=64, 4 waves, each 64x64 via 4x4 of 16x16x32 MFMA.
enum { EP_BF16 = 0, EP_SILU = 1, EP_F32 = 2, EP_SCATTER = 3 };

template <bool ROUTED, bool GATHER, int EP>
__global__ __launch_bounds__(256, 2)
void gemm_bt(const ushort_t* __restrict__ A, const ushort_t* __restrict__ Wb,
             const float* __restrict__ bias, void* __restrict__ Cv,
             int N, int K,
             const int* __restrict__ meta, const int* __restrict__ tok_list,
             const float* __restrict__ slot_w, float* __restrict__ out) {
  int bm = blockIdx.y, bn = blockIdx.x;
  const ushort_t* Wp = Wb;
  const float* bp = bias;
  int rowend = 0x7fffffff;
  if (ROUTED) {
    if (bm >= meta[17]) return;
    int e = meta[18 + bm];
    Wp += (size_t)e * N * K;
    bp += (size_t)e * N;
    rowend = meta[8 + e] + meta[e];
  }
  __shared__ __align__(16) ushort_t As[128 * 64];
  __shared__ __align__(16) ushort_t Bs[128 * 64];
  int tid = threadIdx.x, wave = tid >> 6, lane = tid & 63;

  const ushort_t* agp[4];
  const ushort_t* bgp[4];
  ushort_t* alp[4];
  ushort_t* blp[4];
#pragma unroll
  for (int j = 0; j < 4; ++j) {
    int sr = (wave * 4 + j) * 8 + (lane >> 3);   // 0..127 row within tile
    int c = (lane & 7) * 8;                      // 0..56 col (bf16 elems)
    int slot = bm * 128 + sr;
    int arow;
    if (GATHER) arow = (slot < rowend) ? tok_list[slot] : 0;
    else        arow = slot;
    agp[j] = A + (size_t)arow * K + c;
    bgp[j] = Wp + (size_t)(bn * 128 + sr) * K + c;
    alp[j] = &As[(wave * 4 + j) * 512];
    blp[j] = &Bs[(wave * 4 + j) * 512];
  }

  f32x4 acc[4][4];
  const f32x4 zero = {0.f, 0.f, 0.f, 0.f};
#pragma unroll
  for (int i = 0; i < 4; ++i)
#pragma unroll
    for (int j = 0; j < 4; ++j) acc[i][j] = zero;

  int wm = wave >> 1, wn = wave & 1;
  int fr = lane & 15, fq = lane >> 4;
  int aoff[4], boff[4];
#pragma unroll
  for (int i = 0; i < 4; ++i) aoff[i] = (wm * 64 + i * 16 + fr) * 64 + fq * 8;
#pragma unroll
  for (int j = 0; j < 4; ++j) boff[j] = (wn * 64 + j * 16 + fr) * 64 + fq * 8;

  for (int k0 = 0; k0 < K; k0 += 64) {
#pragma unroll
    for (int j = 0; j < 4; ++j) {
      __builtin_amdgcn_global_load_lds((const AS1 unsigned*)(agp[j] + k0), (AS3 unsigned*)alp[j], 16, 0, 0);
      __builtin_amdgcn_global_load_lds((const AS1 unsigned*)(bgp[j] + k0), (AS3 unsigned*)blp[j], 16, 0, 0);
    }
    __syncthreads();
#pragma unroll
    for (int kk = 0; kk < 64; kk += 32) {
      s16x8 af[4], bfr[4];
#pragma unroll
      for (int i = 0; i < 4; ++i) af[i] = *(const s16x8*)&As[aoff[i] + kk];
#pragma unroll
      for (int j = 0; j < 4; ++j) bfr[j] = *(const s16x8*)&Bs[boff[j] + kk];
#pragma unroll
      for (int i = 0; i < 4; ++i)
#pragma unroll
        for (int j = 0; j < 4; ++j)
          acc[i][j] = __builtin_amdgcn_mfma_f32_16x16x32_bf16(af[i], bfr[j], acc[i][j], 0, 0, 0);
    }
    __syncthreads();
  }

  // epilogue: C/D layout col=lane&15, row=(lane>>4)*4+reg
  float bv[4];
  int ccol[4];
#pragma unroll
  for (int j = 0; j < 4; ++j) {
    ccol[j] = bn * 128 + wn * 64 + j * 16 + fr;
    bv[j] = bp[ccol[j]];
  }
#pragma unroll
  for (int i = 0; i < 4; ++i) {
    int row0 = bm * 128 + wm * 64 + i * 16 + fq * 4;
#pragma unroll
    for (int r = 0; r < 4; ++r) {
      int row = row0 + r;
      if (EP == EP_SCATTER) {
        if (row < rowend) {
          int token = tok_list[row];
          float w = slot_w[row];
          size_t ob = (size_t)token * N;
#pragma unroll
          for (int j = 0; j < 4; ++j)
            atomicAdd(&out[ob + ccol[j]], w * (acc[i][j][r] + bv[j]));
        }
      } else {
        size_t rb = (size_t)row * N;
#pragma unroll
        for (int j = 0; j < 4; ++j) {
          float v = acc[i][j][r] + bv[j];
          if (EP == EP_F32) {
            ((float*)Cv)[rb + ccol[j]] = v;
          } else if (EP == EP_SILU) {
            float g1 = bf2f(((const ushort_t*)Cv)[rb + ccol[j]]);
            float hv = g1 / (1.f + expf(-g1)) * v;
            ((ushort_t*)Cv)[rb + ccol[j]] = f2bf(hv);
          } else {
            ((ushort_t*)Cv)[rb + ccol[j]] = f2bf(v);
          }
        }
      }
    }
  }
}

extern "C" void kernel_launch(void* const* d_in, const int* in_sizes, int n_in,
                              void* d_out, int out_size, void* d_ws, size_t ws_size,
                              hipStream_t stream) {
  const float* x   = (const float*)d_in[0];
  const float* gw  = (const float*)d_in[1];
  const float* gb  = (const float*)d_in[2];
  const float* w1  = (const float*)d_in[3];
  const float* b1  = (const float*)d_in[4];
  const float* w2  = (const float*)d_in[5];
  const float* b2  = (const float*)d_in[6];
  const float* w3  = (const float*)d_in[7];
  const float* b3  = (const float*)d_in[8];
  const float* sw1 = (const float*)d_in[9];
  const float* sb1 = (const float*)d_in[10];
  const float* sw2 = (const float*)d_in[11];
  const float* sb2 = (const float*)d_in[12];
  const float* sw3 = (const float*)d_in[13];
  const float* sb3 = (const float*)d_in[14];
  float* out = (float*)d_out;
  (void)in_sizes; (void)n_in; (void)out_size; (void)ws_size;

  char* ws = (char*)d_ws;
  size_t o = 0;
  auto alloc = [&](size_t bytes) -> void* {
    void* p = ws + o;
    o = (o + bytes + 255) & ~(size_t)255;
    return p;
  };
  // total ~122 MB
  ushort_t* Xb   = (ushort_t*)alloc((size_t)NTOK * D * 2);          // 16 MB
  ushort_t* Wbuf = (ushort_t*)alloc((size_t)E * H * D * 2);         // 32 MB, reused 6x
  ushort_t* Hb   = (ushort_t*)alloc((size_t)MAXROWS * H * 2);       // 68 MB (also shared [8192,4096])
  int*   meta     = (int*)alloc(1024);
  int*   tok_list = (int*)alloc((size_t)MAXROWS * 4);
  float* slot_w   = (float*)alloc((size_t)MAXROWS * 4);
  int*   te       = (int*)alloc((size_t)NTOK * 2 * 4);
  int*   trank    = (int*)alloc((size_t)NTOK * 2 * 4);
  float* tw       = (float*)alloc((size_t)NTOK * 2 * 4);

  auto conv = [&](const float* s, ushort_t* dp, size_t n) {
    int n4 = (int)(n / 4);
    int blocks = (n4 + 255) / 256;
    if (blocks > 2048) blocks = 2048;
    f2bf_kernel<<<blocks, 256, 0, stream>>>(s, dp, n4);
  };

  // routing (uses f32 x directly) — no contended atomics
  zero_counts<<<1, 64, 0, stream>>>(meta);
  gate2_kernel<<<NTOK / 4, 256, 0, stream>>>(x, gw, gb, te, tw);
  rank_kernel<<<NTOK * 2 / 512, 256, 0, stream>>>(te, trank, meta);
  offsets_kernel<<<1, 1, 0, stream>>>(meta);
  scatter_kernel<<<(NTOK * 2 + 255) / 256, 256, 0, stream>>>(te, trank, tw, meta, tok_list, slot_w);

  conv(x, Xb, (size_t)NTOK * D);

  // ---- shared expert first: writes d_out (f32, overwrite) ----
  conv(sw1, Wbuf, (size_t)HS * D);
  gemm_bt<false, false, EP_BF16><<<dim3(HS / 128, NTOK / 128), 256, 0, stream>>>(
      Xb, Wbuf, sb1, (void*)Hb, HS, D, nullptr, nullptr, nullptr, nullptr);
  conv(sw3, Wbuf, (size_t)HS * D);
  gemm_bt<false, false, EP_SILU><<<dim3(HS / 128, NTOK / 128), 256, 0, stream>>>(
      Xb, Wbuf, sb3, (void*)Hb, HS, D, nullptr, nullptr, nullptr, nullptr);
  conv(sw2, Wbuf, (size_t)D * HS);
  gemm_bt<false, false, EP_F32><<<dim3(D / 128, NTOK / 128), 256, 0, stream>>>(
      Hb, Wbuf, sb2, (void*)d_out, D, HS, nullptr, nullptr, nullptr, nullptr);

  // ---- routed experts: atomic-add into d_out ----
  conv(w1, Wbuf, (size_t)E * H * D);
  gemm_bt<true, true, EP_BF16><<<dim3(H / 128, MAXBLK), 256, 0, stream>>>(
      Xb, Wbuf, b1, (void*)Hb, H, D, meta, tok_list, nullptr, nullptr);
  conv(w3, Wbuf, (size_t)E * H * D);
  gemm_bt<true, true, EP_SILU><<<dim3(H / 128, MAXBLK), 256, 0, stream>>>(
      Xb, Wbuf, b3, (void*)Hb, H, D, meta, tok_list, nullptr, nullptr);
  conv(w2, Wbuf, (size_t)E * D * H);
  gemm_bt<true, false, EP_SCATTER><<<dim3(D / 128, MAXBLK), 256, 0, stream>>>(
      Hb, Wbuf, b2, nullptr, D, H, meta, tok_list, slot_w, out);
}

// Round 4
// 874.318 us; speedup vs baseline: 1.2692x; 1.0728x over previous
//
#include <hip/hip_runtime.h>
#include <stdint.h>

#define AS1 __attribute__((address_space(1)))
#define AS3 __attribute__((address_space(3)))

typedef float f32x4 __attribute__((ext_vector_type(4)));
typedef short s16x8 __attribute__((ext_vector_type(8)));
typedef unsigned short ushort_t;

static constexpr int D    = 1024;   // embedding dim
static constexpr int H    = 2048;   // expert hidden
static constexpr int E    = 8;      // experts
static constexpr int NTOK = 8192;   // B*S
static constexpr int HS   = 4096;   // shared hidden
static constexpr int MAXROWS = NTOK * 2 + E * 128;  // 17408 worst-case padded routed rows
static constexpr int MAXBLK  = MAXROWS / 128;       // 136

__device__ __forceinline__ ushort_t f2bf(float f) {
  union { float f; unsigned u; } v; v.f = f;
  unsigned r = v.u + 0x7fffu + ((v.u >> 16) & 1u);   // RNE
  return (ushort_t)(r >> 16);
}
__device__ __forceinline__ float bf2f(ushort_t h) {
  union { unsigned u; float f; } v; v.u = ((unsigned)h) << 16;
  return v.f;
}

// ---------------- f32 -> bf16 conversion ----------------
__global__ void f2bf_kernel(const float* __restrict__ src, ushort_t* __restrict__ dst, int n4) {
  int i = blockIdx.x * blockDim.x + threadIdx.x;
  int stride = gridDim.x * blockDim.x;
  for (; i < n4; i += stride) {
    float4 v = ((const float4*)src)[i];
    ushort4 o;
    o.x = f2bf(v.x); o.y = f2bf(v.y); o.z = f2bf(v.z); o.w = f2bf(v.w);
    ((ushort4*)dst)[i] = o;
  }
}

// ---------------- routing ----------------
// meta ints: [0..7] counts, [8..15] padded offsets, [16] total padded rows,
//            [17] nblk, [18..18+MAXBLK) blk->expert
__global__ void zero_counts(int* meta) { if (threadIdx.x < E) meta[threadIdx.x] = 0; }

// gate: NO atomics — per-token top2 + weights only. 4 waves/block, wave = token.
__global__ void gate2_kernel(const float* __restrict__ x, const float* __restrict__ gw,
                             const float* __restrict__ gb, int* __restrict__ te,
                             float* __restrict__ tw) {
  int wave = threadIdx.x >> 6, lane = threadIdx.x & 63;
  int t = blockIdx.x * 4 + wave;
  const float* xr = x + (size_t)t * D;
  float acc[E];
#pragma unroll
  for (int e = 0; e < E; ++e) acc[e] = 0.f;
  for (int it = 0; it < D / 64; ++it) {
    int d = lane + it * 64;
    float xd = xr[d];
#pragma unroll
    for (int e = 0; e < E; ++e) acc[e] += xd * gw[e * D + d];
  }
#pragma unroll
  for (int e = 0; e < E; ++e)
    for (int s = 32; s > 0; s >>= 1) acc[e] += __shfl_down(acc[e], s);
  if (lane == 0) {
    float lg[E], m = -1e30f;
#pragma unroll
    for (int e = 0; e < E; ++e) { lg[e] = acc[e] + gb[e]; m = fmaxf(m, lg[e]); }
    float z = 0.f, p[E];
#pragma unroll
    for (int e = 0; e < E; ++e) { p[e] = expf(lg[e] - m); z += p[e]; }
#pragma unroll
    for (int e = 0; e < E; ++e) p[e] /= z;
    int i0 = 0;
#pragma unroll
    for (int e = 1; e < E; ++e) if (p[e] > p[i0]) i0 = e;
    int i1 = (i0 == 0) ? 1 : 0;
#pragma unroll
    for (int e = 0; e < E; ++e) if (e != i0 && p[e] > p[i1]) i1 = e;
    float s = p[i0] + p[i1] + 1e-20f;
    te[2 * t] = i0; te[2 * t + 1] = i1;
    tw[2 * t] = p[i0] / s; tw[2 * t + 1] = p[i1] / s;
  }
}

// rank: two-level aggregation. 32 blocks x 256 threads, 2 entries/thread.
__global__ void rank_kernel(const int* __restrict__ te, int* __restrict__ trank,
                            int* __restrict__ meta) {
  __shared__ int hist[E];
  __shared__ int base[E];
  int tid = threadIdx.x;
  if (tid < E) hist[tid] = 0;
  __syncthreads();
  int i0 = blockIdx.x * 512 + tid;
  int i1 = i0 + 256;
  int e0 = te[i0], e1 = te[i1];
  int l0 = atomicAdd(&hist[e0], 1);
  int l1 = atomicAdd(&hist[e1], 1);
  __syncthreads();
  if (tid < E) base[tid] = atomicAdd(&meta[tid], hist[tid]);
  __syncthreads();
  trank[i0] = base[e0] + l0;
  trank[i1] = base[e1] + l1;
}

__global__ void offsets_kernel(int* meta) {
  if (threadIdx.x != 0 || blockIdx.x != 0) return;
  int off = 0;
  for (int e = 0; e < E; ++e) {
    meta[8 + e] = off;
    int nb = (meta[e] + 127) >> 7;
    int b0 = off >> 7;
    for (int b = 0; b < nb; ++b) meta[18 + b0 + b] = e;
    off += nb << 7;
  }
  meta[16] = off;
  meta[17] = off >> 7;
}

__global__ void scatter_kernel(const int* __restrict__ te, const int* __restrict__ trank,
                               const float* __restrict__ tw, const int* __restrict__ meta,
                               int* __restrict__ tok_list, float* __restrict__ slot_w) {
  int i = blockIdx.x * blockDim.x + threadIdx.x;
  if (i >= NTOK * 2) return;
  int e = te[i];
  int slot = meta[8 + e] + trank[i];
  tok_list[slot] = i >> 1;
  slot_w[slot] = tw[i];
}

// ---------------- bf16 MFMA GEMM: C[M,N] = A @ W^T (+ bias) ----------------
// A: [*, K] bf16 (rows optionally gathered via tok_list)
// W: [E?, N, K] bf16 row-major (torch Linear layout)
// 128x128 tile, BK=64, 4 waves, each 64x64 via 4x4 of 16x16x32 MFMA.
// LDS layout is XOR-swizzled (16B unit column ^= row&7) to kill the 128B-stride
// bank conflicts that the lane-ordered global_load_lds layout otherwise forces:
// bank group of (r,c8) = c8 ^ (r&7) -> each of 8 groups serves exactly 8 lanes.
enum { EP_BF16 = 0, EP_SILU = 1, EP_F32 = 2, EP_SCATTER = 3 };

__device__ __forceinline__ int swz_off(int r, int c8) {
  // element offset of the 8-elem (16B) unit at row r, unit-col c8, in a
  // [8 rows x 8 units] 1KB chunk layout, chunks stacked every 512 elems
  return ((r >> 3) * 64 + (r & 7) * 8 + ((c8 ^ (r & 7)))) * 8;
}

template <bool ROUTED, bool GATHER, int EP>
__global__ __launch_bounds__(256, 2)
void gemm_bt(const ushort_t* __restrict__ A, const ushort_t* __restrict__ Wb,
             const float* __restrict__ bias, void* __restrict__ Cv,
             int N, int K,
             const int* __restrict__ meta, const int* __restrict__ tok_list,
             const float* __restrict__ slot_w, float* __restrict__ out) {
  int bm = blockIdx.y, bn = blockIdx.x;
  const ushort_t* Wp = Wb;
  const float* bp = bias;
  int rowend = 0x7fffffff;
  if (ROUTED) {
    if (bm >= meta[17]) return;
    int e = meta[18 + bm];
    Wp += (size_t)e * N * K;
    bp += (size_t)e * N;
    rowend = meta[8 + e] + meta[e];
  }
  __shared__ __align__(16) ushort_t As[128 * 64];
  __shared__ __align__(16) ushort_t Bs[128 * 64];
  int tid = threadIdx.x, wave = tid >> 6, lane = tid & 63;

  // staging: lane L covers (row = L>>3, unit-col = (L&7) ^ (L>>3)) of each
  // 8-row chunk; LDS side is hardware-fixed at chunk_base + L*16B.
  int rin  = lane >> 3;
  int col8 = (lane & 7) ^ rin;
  const ushort_t* agp[4];
  const ushort_t* bgp[4];
  ushort_t* alp[4];
  ushort_t* blp[4];
#pragma unroll
  for (int j = 0; j < 4; ++j) {
    int sr = (wave * 4 + j) * 8 + rin;   // 0..127 row within tile
    int c = col8 * 8;                    // swizzled 16B unit -> bf16 col
    int slot = bm * 128 + sr;
    int arow;
    if (GATHER) arow = (slot < rowend) ? tok_list[slot] : 0;
    else        arow = slot;
    agp[j] = A + (size_t)arow * K + c;
    bgp[j] = Wp + (size_t)(bn * 128 + sr) * K + c;
    alp[j] = &As[(wave * 4 + j) * 512];
    blp[j] = &Bs[(wave * 4 + j) * 512];
  }

  f32x4 acc[4][4];
  const f32x4 zero = {0.f, 0.f, 0.f, 0.f};
#pragma unroll
  for (int i = 0; i < 4; ++i)
#pragma unroll
    for (int j = 0; j < 4; ++j) acc[i][j] = zero;

  int wm = wave >> 1, wn = wave & 1;
  int fr = lane & 15, fq = lane >> 4;
  int aoff[4][2], boff[4][2];
#pragma unroll
  for (int i = 0; i < 4; ++i) {
    int r = wm * 64 + i * 16 + fr;
    aoff[i][0] = swz_off(r, fq);
    aoff[i][1] = swz_off(r, fq + 4);
  }
#pragma unroll
  for (int j = 0; j < 4; ++j) {
    int r = wn * 64 + j * 16 + fr;
    boff[j][0] = swz_off(r, fq);
    boff[j][1] = swz_off(r, fq + 4);
  }

  for (int k0 = 0; k0 < K; k0 += 64) {
#pragma unroll
    for (int j = 0; j < 4; ++j) {
      __builtin_amdgcn_global_load_lds((const AS1 unsigned*)(agp[j] + k0), (AS3 unsigned*)alp[j], 16, 0, 0);
      __builtin_amdgcn_global_load_lds((const AS1 unsigned*)(bgp[j] + k0), (AS3 unsigned*)blp[j], 16, 0, 0);
    }
    __syncthreads();
#pragma unroll
    for (int kidx = 0; kidx < 2; ++kidx) {
      s16x8 af[4], bfr[4];
#pragma unroll
      for (int i = 0; i < 4; ++i) af[i] = *(const s16x8*)&As[aoff[i][kidx]];
#pragma unroll
      for (int j = 0; j < 4; ++j) bfr[j] = *(const s16x8*)&Bs[boff[j][kidx]];
#pragma unroll
      for (int i = 0; i < 4; ++i)
#pragma unroll
        for (int j = 0; j < 4; ++j)
          acc[i][j] = __builtin_amdgcn_mfma_f32_16x16x32_bf16(af[i], bfr[j], acc[i][j], 0, 0, 0);
    }
    __syncthreads();
  }

  // epilogue: C/D layout col=lane&15, row=(lane>>4)*4+reg
  float bv[4];
  int ccol[4];
#pragma unroll
  for (int j = 0; j < 4; ++j) {
    ccol[j] = bn * 128 + wn * 64 + j * 16 + fr;
    bv[j] = bp[ccol[j]];
  }
#pragma unroll
  for (int i = 0; i < 4; ++i) {
    int row0 = bm * 128 + wm * 64 + i * 16 + fq * 4;
#pragma unroll
    for (int r = 0; r < 4; ++r) {
      int row = row0 + r;
      if (EP == EP_SCATTER) {
        if (row < rowend) {
          int token = tok_list[row];
          float w = slot_w[row];
          size_t ob = (size_t)token * N;
#pragma unroll
          for (int j = 0; j < 4; ++j)
            atomicAdd(&out[ob + ccol[j]], w * (acc[i][j][r] + bv[j]));
        }
      } else {
        size_t rb = (size_t)row * N;
#pragma unroll
        for (int j = 0; j < 4; ++j) {
          float v = acc[i][j][r] + bv[j];
          if (EP == EP_F32) {
            ((float*)Cv)[rb + ccol[j]] = v;
          } else if (EP == EP_SILU) {
            float g1 = bf2f(((const ushort_t*)Cv)[rb + ccol[j]]);
            float hv = g1 / (1.f + expf(-g1)) * v;
            ((ushort_t*)Cv)[rb + ccol[j]] = f2bf(hv);
          } else {
            ((ushort_t*)Cv)[rb + ccol[j]] = f2bf(v);
          }
        }
      }
    }
  }
}

extern "C" void kernel_launch(void* const* d_in, const int* in_sizes, int n_in,
                              void* d_out, int out_size, void* d_ws, size_t ws_size,
                              hipStream_t stream) {
  const float* x   = (const float*)d_in[0];
  const float* gw  = (const float*)d_in[1];
  const float* gb  = (const float*)d_in[2];
  const float* w1  = (const float*)d_in[3];
  const float* b1  = (const float*)d_in[4];
  const float* w2  = (const float*)d_in[5];
  const float* b2  = (const float*)d_in[6];
  const float* w3  = (const float*)d_in[7];
  const float* b3  = (const float*)d_in[8];
  const float* sw1 = (const float*)d_in[9];
  const float* sb1 = (const float*)d_in[10];
  const float* sw2 = (const float*)d_in[11];
  const float* sb2 = (const float*)d_in[12];
  const float* sw3 = (const float*)d_in[13];
  const float* sb3 = (const float*)d_in[14];
  float* out = (float*)d_out;
  (void)in_sizes; (void)n_in; (void)out_size; (void)ws_size;

  char* ws = (char*)d_ws;
  size_t o = 0;
  auto alloc = [&](size_t bytes) -> void* {
    void* p = ws + o;
    o = (o + bytes + 255) & ~(size_t)255;
    return p;
  };
  // total ~122 MB
  ushort_t* Xb   = (ushort_t*)alloc((size_t)NTOK * D * 2);          // 16 MB
  ushort_t* Wbuf = (ushort_t*)alloc((size_t)E * H * D * 2);         // 32 MB, reused 6x
  ushort_t* Hb   = (ushort_t*)alloc((size_t)MAXROWS * H * 2);       // 68 MB (also shared [8192,4096])
  int*   meta     = (int*)alloc(1024);
  int*   tok_list = (int*)alloc((size_t)MAXROWS * 4);
  float* slot_w   = (float*)alloc((size_t)MAXROWS * 4);
  int*   te       = (int*)alloc((size_t)NTOK * 2 * 4);
  int*   trank    = (int*)alloc((size_t)NTOK * 2 * 4);
  float* tw       = (float*)alloc((size_t)NTOK * 2 * 4);

  auto conv = [&](const float* s, ushort_t* dp, size_t n) {
    int n4 = (int)(n / 4);
    int blocks = (n4 + 255) / 256;
    if (blocks > 2048) blocks = 2048;
    f2bf_kernel<<<blocks, 256, 0, stream>>>(s, dp, n4);
  };

  // routing (uses f32 x directly) — no contended atomics
  zero_counts<<<1, 64, 0, stream>>>(meta);
  gate2_kernel<<<NTOK / 4, 256, 0, stream>>>(x, gw, gb, te, tw);
  rank_kernel<<<NTOK * 2 / 512, 256, 0, stream>>>(te, trank, meta);
  offsets_kernel<<<1, 1, 0, stream>>>(meta);
  scatter_kernel<<<(NTOK * 2 + 255) / 256, 256, 0, stream>>>(te, trank, tw, meta, tok_list, slot_w);

  conv(x, Xb, (size_t)NTOK * D);

  // ---- shared expert first: writes d_out (f32, overwrite) ----
  conv(sw1, Wbuf, (size_t)HS * D);
  gemm_bt<false, false, EP_BF16><<<dim3(HS / 128, NTOK / 128), 256, 0, stream>>>(
      Xb, Wbuf, sb1, (void*)Hb, HS, D, nullptr, nullptr, nullptr, nullptr);
  conv(sw3, Wbuf, (size_t)HS * D);
  gemm_bt<false, false, EP_SILU><<<dim3(HS / 128, NTOK / 128), 256, 0, stream>>>(
      Xb, Wbuf, sb3, (void*)Hb, HS, D, nullptr, nullptr, nullptr, nullptr);
  conv(sw2, Wbuf, (size_t)D * HS);
  gemm_bt<false, false, EP_F32><<<dim3(D / 128, NTOK / 128), 256, 0, stream>>>(
      Hb, Wbuf, sb2, (void*)d_out, D, HS, nullptr, nullptr, nullptr, nullptr);

  // ---- routed experts: atomic-add into d_out ----
  conv(w1, Wbuf, (size_t)E * H * D);
  gemm_bt<true, true, EP_BF16><<<dim3(H / 128, MAXBLK), 256, 0, stream>>>(
      Xb, Wbuf, b1, (void*)Hb, H, D, meta, tok_list, nullptr, nullptr);
  conv(w3, Wbuf, (size_t)E * H * D);
  gemm_bt<true, true, EP_SILU><<<dim3(H / 128, MAXBLK), 256, 0, stream>>>(
      Xb, Wbuf, b3, (void*)Hb, H, D, meta, tok_list, nullptr, nullptr);
  conv(w2, Wbuf, (size_t)E * D * H);
  gemm_bt<true, false, EP_SCATTER><<<dim3(D / 128, MAXBLK), 256, 0, stream>>>(
      Hb, Wbuf, b2, nullptr, D, H, meta, tok_list, slot_w, out);
}